// Round 11
// baseline (200.654 us; speedup 1.0000x reference)
//
#include <hip/hip_runtime.h>

#define NROIS 512
#define NEDGES 262144

// ---------------------------------------------------------------------------
// edge_index may arrive as int64 (reference dtype) or int32 (harness downcast).
__device__ __forceinline__ int detect_i64(const unsigned* __restrict__ er) {
    unsigned acc = 0;
#pragma unroll
    for (int i = 0; i < 64; ++i) acc |= er[2 * i + 1];
    return acc == 0u;
}

__device__ __forceinline__ void load_edge(const unsigned* __restrict__ er,
                                          bool i64, int e, int& src, int& dst) {
    if (i64) { src = (int)er[2 * e]; dst = (int)er[2 * NEDGES + 2 * e]; }
    else     { src = (int)er[e];     dst = (int)er[NEDGES + e]; }
}

// ---------------------------------------------------------------------------
// prep: pack weight rows lwT[r][8] = {lb[r], lw[0][r]..lw[5][r], 0} for all
// three layers -> per-(i,o) weights become ONE s_load_dwordx8 (rounds 8/9
// died on 6048 scattered scalar-dword issues per edge-round per wave).
__global__ __launch_bounds__(256) void prep_kernel(
    const float* __restrict__ lw1, const float* __restrict__ lb1,
    const float* __restrict__ lw2, const float* __restrict__ lb2,
    const float* __restrict__ lw3, const float* __restrict__ lb3,
    float* __restrict__ lwT1, float* __restrict__ lwT2, float* __restrict__ lwT3)
{
    const int t = threadIdx.x;
    for (int r = t; r < 36; r += 256) {
        lwT1[r * 8] = lb1[r];
#pragma unroll
        for (int v = 0; v < 6; ++v) lwT1[r * 8 + 1 + v] = lw1[v * 36 + r];
        lwT1[r * 8 + 7] = 0.f;
    }
    for (int r = t; r < 864; r += 256) {
        lwT2[r * 8] = lb2[r];
#pragma unroll
        for (int v = 0; v < 6; ++v) lwT2[r * 8 + 1 + v] = lw2[v * 864 + r];
        lwT2[r * 8 + 7] = 0.f;
    }
    for (int r = t; r < 120; r += 256) {
        lwT3[r * 8] = lb3[r];
#pragma unroll
        for (int v = 0; v < 6; ++v) lwT3[r * 8 + 1 + v] = lw3[v * 120 + r];
        lwT3[r * 8 + 7] = 0.f;
    }
}

// ---------------------------------------------------------------------------
// hist: 64 blocks x 4096 edges, per-block LDS hist -> gpart[64][512]
__global__ __launch_bounds__(256) void hist_kernel(const unsigned* __restrict__ er,
                                                   int* __restrict__ gpart)
{
    __shared__ int lh[NROIS];
    __shared__ int s_l;
    const int t = threadIdx.x;
    if (t == 0) s_l = detect_i64(er);
    for (int i = t; i < NROIS; i += 256) lh[i] = 0;
    __syncthreads();
    const bool L = (s_l != 0);
    const int e0 = blockIdx.x * 4096;
#pragma unroll
    for (int k = 0; k < 16; ++k) {
        int e = e0 + k * 256 + t, src, dst;
        load_edge(er, L, e, src, dst);
        atomicAdd(&lh[dst], 1);
    }
    __syncthreads();
    for (int i = t; i < NROIS; i += 256) gpart[blockIdx.x * NROIS + i] = lh[i];
}

// scan: sum 64 partials per bin, inclusive scan -> start[513], cursor (exclusive)
__global__ __launch_bounds__(512) void scan_kernel(const int* __restrict__ gpart,
                                                   int* __restrict__ start,
                                                   int* __restrict__ cursor)
{
    __shared__ int tmp[NROIS];
    const int t = threadIdx.x;
    int own = 0;
#pragma unroll 8
    for (int b = 0; b < 64; ++b) own += gpart[b * NROIS + t];
    tmp[t] = own;
    __syncthreads();
    for (int off = 1; off < NROIS; off <<= 1) {
        int v = tmp[t];
        int add = (t >= off) ? tmp[t - off] : 0;
        __syncthreads();
        tmp[t] = v + add;
        __syncthreads();
    }
    start[t + 1] = tmp[t];
    if (t == 0) start[0] = 0;
    cursor[t] = tmp[t] - own;            // exclusive prefix
}

// scatter + fused pack: 256 blocks x 1024 edges. Per-block LDS bucketing, one
// global atomic per (block,bin). packed: eas rows only; else perm.
__global__ __launch_bounds__(256) void scatter_kernel(const unsigned* __restrict__ er,
                                                      const float* __restrict__ ea,
                                                      int* __restrict__ gcursor,
                                                      unsigned* __restrict__ perm,
                                                      float* __restrict__ eas,
                                                      int packed)
{
    __shared__ int lh[NROIS];
    __shared__ int lbase[NROIS];
    __shared__ int s_l;
    const int t = threadIdx.x;
    if (t == 0) s_l = detect_i64(er);
    for (int i = t; i < NROIS; i += 256) lh[i] = 0;
    __syncthreads();
    const bool L = (s_l != 0);
    const int e0 = blockIdx.x * 1024;
#pragma unroll
    for (int k = 0; k < 4; ++k) {
        int e = e0 + k * 256 + t, src, dst;
        load_edge(er, L, e, src, dst);
        atomicAdd(&lh[dst], 1);
    }
    __syncthreads();
    for (int i = t; i < NROIS; i += 256) {
        int c = lh[i];
        lbase[i] = c ? atomicAdd(&gcursor[i], c) : 0;
    }
    __syncthreads();
#pragma unroll
    for (int k = 0; k < 4; ++k) {
        int e = e0 + k * 256 + t, src, dst;
        load_edge(er, L, e, src, dst);
        int pos = atomicAdd(&lbase[dst], 1);
        unsigned ps = ((unsigned)e << 9) | (unsigned)src;
        if (packed) {
            const float2* s = reinterpret_cast<const float2*>(ea + (size_t)e * 6);
            const float2 a0 = s[0], a1 = s[1], a2 = s[2];
            float4* d = reinterpret_cast<float4*>(eas + (size_t)pos * 8);
            d[0] = make_float4(a0.x, a0.y, a1.x, a1.y);
            d[1] = make_float4(a2.x, a2.y, __uint_as_float(ps), 0.f);
        } else {
            perm[pos] = ps;
        }
    }
}

// ---------------------------------------------------------------------------
// Fused NNConv layer: block (chunk, dst); LANE OWNS AN EDGE; per-lane state is
// only a[6]+acc[COUT] (accumulators can't be remat'd - rounds 4-10 showed any
// OTHER per-lane persistent array gets remat'd/spilled). Weights stream on the
// scalar path as ONE s_load_dwordx8 per (i,o) from the packed table. i-split
// (NSPLIT chunks of CINH) keeps LDS small for occupancy. Invalid lanes read a
// zeroed LDS row -> no divergence. NSPLIT==1 fuses the node update.
template <int CIN, int CINH, int COUT, int STR, int NSPLIT, bool PACKED>
__global__ __launch_bounds__(256) void layer_kernel(
    const float* __restrict__ eas, const float* __restrict__ ea,
    const unsigned* __restrict__ perm, const int* __restrict__ start,
    const float* __restrict__ lwT, const float* __restrict__ root,
    const float* __restrict__ bias, const float* __restrict__ hin,
    float* __restrict__ out)
{
    __shared__ float sh[NROIS * STR + CINH];   // + zero row for invalid lanes
    __shared__ float red[4 * COUT];
    const int t = threadIdx.x;
    const int chunk = blockIdx.x;
    const int ibase = chunk * CINH;

    // stage hin[:, ibase:ibase+CINH] -> sh [NROIS][STR] (odd STR spreads banks)
    for (int idx = t; idx < NROIS * CINH; idx += 256) {
        const int r = idx / CINH;
        sh[r * STR + (idx - r * CINH)] = hin[r * CIN + ibase + (idx - r * CINH)];
    }
    if (t < CINH) sh[NROIS * STR + t] = 0.f;
    __syncthreads();

    const int dst = blockIdx.y;
    const int s0 = start[dst], c1 = start[dst + 1];
    const int cnt = c1 - s0;

    float acc[COUT];
#pragma unroll
    for (int o = 0; o < COUT; ++o) acc[o] = 0.f;

    const int nr = (cnt + 255) / 256;
    for (int r = 0; r < nr; ++r) {
        const int idx = s0 + r * 256 + t;
        const bool val = (idx < c1);
        const int eidx = val ? idx : s0;
        float a0, a1, a2, a3, a4, a5;
        unsigned ps;
        if constexpr (PACKED) {
            const float4* __restrict__ base = reinterpret_cast<const float4*>(eas);
            const float4 r0 = base[2 * eidx], r1 = base[2 * eidx + 1];
            a0 = r0.x; a1 = r0.y; a2 = r0.z; a3 = r0.w;
            a4 = r1.x; a5 = r1.y; ps = __float_as_uint(r1.z);
        } else {
            ps = perm[eidx];
            const float* __restrict__ ap = ea + (size_t)(ps >> 9) * 6;
            a0 = ap[0]; a1 = ap[1]; a2 = ap[2]; a3 = ap[3]; a4 = ap[4]; a5 = ap[5];
        }
        const int hb = val ? (int)(ps & 511u) * STR : NROIS * STR;

#pragma unroll 2
        for (int i = 0; i < CINH; ++i) {
            const float hsv = sh[hb + i];
            const float* __restrict__ wrow = lwT + (size_t)(ibase + i) * COUT * 8;
#pragma unroll
            for (int o = 0; o < COUT; ++o) {
                // wrow index wave-uniform -> one s_load_dwordx8 per (i,o)
                const float* __restrict__ w8 = wrow + o * 8;
                float tt = w8[0];
                tt = fmaf(a0, w8[1], tt);
                tt = fmaf(a1, w8[2], tt);
                tt = fmaf(a2, w8[3], tt);
                tt = fmaf(a3, w8[4], tt);
                tt = fmaf(a4, w8[5], tt);
                tt = fmaf(a5, w8[6], tt);
                acc[o] = fmaf(hsv, fmaxf(tt, 0.f), acc[o]);
            }
        }
    }

    // 64-lane butterfly reduce, combine 4 waves via LDS
#pragma unroll
    for (int o = 0; o < COUT; ++o) {
        float v = acc[o];
#pragma unroll
        for (int d = 32; d > 0; d >>= 1) v += __shfl_xor(v, d);
        acc[o] = v;
    }
    const int lane = t & 63, wid = t >> 6;
    if (lane == 0) {
#pragma unroll
        for (int o = 0; o < COUT; ++o) red[wid * COUT + o] = acc[o];
    }
    __syncthreads();

    if (t < COUT) {
        float tot = red[t] + red[COUT + t] + red[2 * COUT + t] + red[3 * COUT + t];
        if constexpr (NSPLIT == 1) {
            // fused node update: mean + root term + bias + relu (CINH==CIN)
            float aggr = tot / fmaxf((float)cnt, 1.f);
            float rr = bias[t];
#pragma unroll 4
            for (int k = 0; k < CIN; ++k)
                rr = fmaf(sh[dst * STR + k], root[k * COUT + t], rr);
            out[dst * COUT + t] = fmaxf(aggr + rr, 0.f);
        } else {
            out[((size_t)chunk * NROIS + dst) * COUT + t] = tot;
        }
    }
}

// combine i-chunks + mean + root term + bias + relu (for NSPLIT>1 layers)
template <int CIN, int COUT, int NSPLIT>
__global__ __launch_bounds__(256) void node_kernel(
    const float* __restrict__ hin, const float* __restrict__ partial,
    const int* __restrict__ start, const float* __restrict__ root,
    const float* __restrict__ bias, float* __restrict__ hout)
{
    int t = blockIdx.x * 256 + threadIdx.x;
    if (t >= NROIS * COUT) return;
    int i = t / COUT, o = t - i * COUT;
    float s = 0.f;
#pragma unroll
    for (int c = 0; c < NSPLIT; ++c) s += partial[((size_t)c * NROIS + i) * COUT + o];
    int cnt = start[i + 1] - start[i];
    float aggr = s / fmaxf((float)cnt, 1.f);
    float r = bias[o];
#pragma unroll 4
    for (int k = 0; k < CIN; ++k) r = fmaf(hin[i * CIN + k], root[k * COUT + o], r);
    hout[t] = fmaxf(aggr + r, 0.f);
}

// cbt[i,j] = sum_k |h[i,k]-h[j,k]|, h: [512,5] staged in LDS, block per row i
__global__ __launch_bounds__(256) void cbt_kernel(const float* __restrict__ h,
                                                  float* __restrict__ out)
{
    __shared__ float sh[NROIS * 5];
    for (int t = threadIdx.x; t < NROIS * 5; t += 256) sh[t] = h[t];
    __syncthreads();
    const int i = blockIdx.x;
    float hi[5];
#pragma unroll
    for (int k = 0; k < 5; ++k) hi[k] = sh[i * 5 + k];
    for (int j = threadIdx.x; j < NROIS; j += 256) {
        float s = 0.f;
#pragma unroll
        for (int k = 0; k < 5; ++k) s += fabsf(hi[k] - sh[j * 5 + k]);
        out[i * NROIS + j] = s;
    }
}

// ---------------------------------------------------------------------------
template <bool PACKED>
static void run_layers(const float* x, const float* ea, const unsigned* perm,
                       const int* start,
                       const float* lwT1, const float* root1, const float* b1,
                       const float* lwT2, const float* root2, const float* b2,
                       const float* lwT3, const float* root3, const float* b3,
                       const float* eas, float* part,
                       float* h1, float* h2, float* h3, hipStream_t stream)
{
    // layer 1: cin=1, cout=36, no split, fused node update
    layer_kernel<1, 1, 36, 1, 1, PACKED><<<dim3(1, NROIS), 256, 0, stream>>>(
        eas, ea, perm, start, lwT1, root1, b1, x, h1);
    // layer 2: cin=36 split into 2 chunks of 18 (LDS 39KB -> 4 blocks/CU)
    layer_kernel<36, 18, 24, 19, 2, PACKED><<<dim3(2, NROIS), 256, 0, stream>>>(
        eas, ea, perm, start, lwT2, root2, b2, h1, part);
    node_kernel<36, 24, 2><<<(NROIS * 24 + 255) / 256, 256, 0, stream>>>(
        h1, part, start, root2, b2, h2);
    // layer 3: cin=24, cout=5, no split, fused node update
    layer_kernel<24, 24, 5, 25, 1, PACKED><<<dim3(1, NROIS), 256, 0, stream>>>(
        eas, ea, perm, start, lwT3, root3, b3, h2, h3);
}

extern "C" void kernel_launch(void* const* d_in, const int* in_sizes, int n_in,
                              void* d_out, int out_size, void* d_ws, size_t ws_size,
                              hipStream_t stream)
{
    const float*    x     = (const float*)d_in[0];
    const float*    ea    = (const float*)d_in[1];
    const unsigned* er    = (const unsigned*)d_in[2];
    const float*    lw1   = (const float*)d_in[3];
    const float*    lb1   = (const float*)d_in[4];
    const float*    root1 = (const float*)d_in[5];
    const float*    b1    = (const float*)d_in[6];
    const float*    lw2   = (const float*)d_in[7];
    const float*    lb2   = (const float*)d_in[8];
    const float*    root2 = (const float*)d_in[9];
    const float*    b2    = (const float*)d_in[10];
    const float*    lw3   = (const float*)d_in[11];
    const float*    lb3   = (const float*)d_in[12];
    const float*    root3 = (const float*)d_in[13];
    const float*    b3    = (const float*)d_in[14];

    const size_t easN  = (size_t)NEDGES * 8;                  // floats
    const size_t restN = 8160 + 18432 + 12288 + 2560 + 32768 + 513 + 512 + NEDGES;
    const size_t needPacked = (easN + restN) * 4;
    const int packed = (ws_size >= needPacked) ? 1 : 0;

    float* ws   = (float*)d_ws;
    float* eas  = ws;                                   // 8 MB (packed only)
    float* rest = packed ? (ws + easN) : ws;
    float* lwT1 = rest;                  // 288  (32B-aligned)
    float* lwT2 = lwT1 + 288;            // 6912
    float* lwT3 = lwT2 + 6912;           // 960
    float* h1   = lwT3 + 960;            // 512*36
    float* h2   = h1 + NROIS * 36;       // 512*24
    float* h3   = h2 + NROIS * 24;       // 512*5
    float* part = h3 + NROIS * 5;        // 32768 floats (gpart scratch / L2 partial)
    int* gpart  = (int*)part;            // 64*512 ints, pre-layer only
    int* start  = (int*)(part + 32768);
    int* cursor = start + NROIS + 1;     // 512
    unsigned* perm = (unsigned*)(cursor + NROIS);       // 262144

    // --- prep + counting sort by dst + fused edge-attr pack ---
    prep_kernel<<<1, 256, 0, stream>>>(lw1, lb1, lw2, lb2, lw3, lb3,
                                       lwT1, lwT2, lwT3);
    hist_kernel<<<NEDGES / 4096, 256, 0, stream>>>(er, gpart);
    scan_kernel<<<1, 512, 0, stream>>>(gpart, start, cursor);
    scatter_kernel<<<NEDGES / 1024, 256, 0, stream>>>(er, ea, cursor, perm, eas, packed);

    if (packed)
        run_layers<true>(x, ea, perm, start, lwT1, root1, b1, lwT2, root2, b2,
                         lwT3, root3, b3, eas, part, h1, h2, h3, stream);
    else
        run_layers<false>(x, ea, perm, start, lwT1, root1, b1, lwT2, root2, b2,
                          lwT3, root3, b3, eas, part, h1, h2, h3, stream);

    // --- pairwise L1 distance tail ---
    cbt_kernel<<<NROIS, 256, 0, stream>>>(h3, (float*)d_out);
}

// Round 12
// 197.120 us; speedup vs baseline: 1.0179x; 1.0179x over previous
//
#include <hip/hip_runtime.h>

#define NROIS 512
#define NEDGES 262144
#define NCHMAX 4608   // max wave-chunks: E/64 + NROIS

// ---------------------------------------------------------------------------
// edge_index may arrive as int64 (reference dtype) or int32 (harness downcast).
__device__ __forceinline__ int detect_i64(const unsigned* __restrict__ er) {
    unsigned acc = 0;
#pragma unroll
    for (int i = 0; i < 64; ++i) acc |= er[2 * i + 1];
    return acc == 0u;
}

__device__ __forceinline__ void load_edge(const unsigned* __restrict__ er,
                                          bool i64, int e, int& src, int& dst) {
    if (i64) { src = (int)er[2 * e]; dst = (int)er[2 * NEDGES + 2 * e]; }
    else     { src = (int)er[e];     dst = (int)er[NEDGES + e]; }
}

// ---------------------------------------------------------------------------
// prep: pack weight rows lwT[r][8] = {lb[r], lw[0][r]..lw[5][r], 0} so each
// (i,o) is ONE s_load_dwordx8 on the scalar path.
__global__ __launch_bounds__(256) void prep_kernel(
    const float* __restrict__ lw1, const float* __restrict__ lb1,
    const float* __restrict__ lw2, const float* __restrict__ lb2,
    const float* __restrict__ lw3, const float* __restrict__ lb3,
    float* __restrict__ lwT1, float* __restrict__ lwT2, float* __restrict__ lwT3)
{
    const int t = threadIdx.x;
    for (int r = t; r < 36; r += 256) {
        lwT1[r * 8] = lb1[r];
#pragma unroll
        for (int v = 0; v < 6; ++v) lwT1[r * 8 + 1 + v] = lw1[v * 36 + r];
        lwT1[r * 8 + 7] = 0.f;
    }
    for (int r = t; r < 864; r += 256) {
        lwT2[r * 8] = lb2[r];
#pragma unroll
        for (int v = 0; v < 6; ++v) lwT2[r * 8 + 1 + v] = lw2[v * 864 + r];
        lwT2[r * 8 + 7] = 0.f;
    }
    for (int r = t; r < 120; r += 256) {
        lwT3[r * 8] = lb3[r];
#pragma unroll
        for (int v = 0; v < 6; ++v) lwT3[r * 8 + 1 + v] = lw3[v * 120 + r];
        lwT3[r * 8 + 7] = 0.f;
    }
}

// zero the three ssum accumulators
__global__ __launch_bounds__(256) void zero_kernel(float* __restrict__ p, int n) {
    int t = blockIdx.x * 256 + threadIdx.x;
    if (t < n) p[t] = 0.f;
}

// ---------------------------------------------------------------------------
// hist: 64 blocks x 4096 edges, per-block LDS hist -> gpart[64][512]
__global__ __launch_bounds__(256) void hist_kernel(const unsigned* __restrict__ er,
                                                   int* __restrict__ gpart)
{
    __shared__ int lh[NROIS];
    __shared__ int s_l;
    const int t = threadIdx.x;
    if (t == 0) s_l = detect_i64(er);
    for (int i = t; i < NROIS; i += 256) lh[i] = 0;
    __syncthreads();
    const bool L = (s_l != 0);
    const int e0 = blockIdx.x * 4096;
#pragma unroll
    for (int k = 0; k < 16; ++k) {
        int e = e0 + k * 256 + t, src, dst;
        load_edge(er, L, e, src, dst);
        atomicAdd(&lh[dst], 1);
    }
    __syncthreads();
    for (int i = t; i < NROIS; i += 256) gpart[blockIdx.x * NROIS + i] = lh[i];
}

// scan: start[513] + cursor (for scatter) + wave-chunk map: chstart[513],
// chtotal, map[chunk]=dst  (chunks = ceil(cnt/64) per dst)
__global__ __launch_bounds__(512) void scan_kernel(const int* __restrict__ gpart,
                                                   int* __restrict__ start,
                                                   int* __restrict__ cursor,
                                                   int* __restrict__ chstart,
                                                   int* __restrict__ chtotal,
                                                   int* __restrict__ map)
{
    __shared__ int tmp[NROIS];
    const int t = threadIdx.x;
    int own = 0;
#pragma unroll 8
    for (int b = 0; b < 64; ++b) own += gpart[b * NROIS + t];
    tmp[t] = own;
    __syncthreads();
    for (int off = 1; off < NROIS; off <<= 1) {
        int v = tmp[t];
        int add = (t >= off) ? tmp[t - off] : 0;
        __syncthreads();
        tmp[t] = v + add;
        __syncthreads();
    }
    start[t + 1] = tmp[t];
    if (t == 0) start[0] = 0;
    cursor[t] = tmp[t] - own;            // exclusive prefix

    // second scan: wave-chunks
    const int nch = (own + 63) >> 6;
    __syncthreads();
    tmp[t] = nch;
    __syncthreads();
    for (int off = 1; off < NROIS; off <<= 1) {
        int v = tmp[t];
        int add = (t >= off) ? tmp[t - off] : 0;
        __syncthreads();
        tmp[t] = v + add;
        __syncthreads();
    }
    chstart[t + 1] = tmp[t];
    if (t == 0) chstart[0] = 0;
    if (t == NROIS - 1) chtotal[0] = tmp[t];
    const int cbase = tmp[t] - nch;
    for (int c = 0; c < nch; ++c) map[cbase + c] = t;
}

// scatter + fused pack: 256 blocks x 1024 edges. Per-block LDS bucketing, one
// global atomic per (block,bin). packed: eas rows; else perm.
__global__ __launch_bounds__(256) void scatter_kernel(const unsigned* __restrict__ er,
                                                      const float* __restrict__ ea,
                                                      int* __restrict__ gcursor,
                                                      unsigned* __restrict__ perm,
                                                      float* __restrict__ eas,
                                                      int packed)
{
    __shared__ int lh[NROIS];
    __shared__ int lbase[NROIS];
    __shared__ int s_l;
    const int t = threadIdx.x;
    if (t == 0) s_l = detect_i64(er);
    for (int i = t; i < NROIS; i += 256) lh[i] = 0;
    __syncthreads();
    const bool L = (s_l != 0);
    const int e0 = blockIdx.x * 1024;
#pragma unroll
    for (int k = 0; k < 4; ++k) {
        int e = e0 + k * 256 + t, src, dst;
        load_edge(er, L, e, src, dst);
        atomicAdd(&lh[dst], 1);
    }
    __syncthreads();
    for (int i = t; i < NROIS; i += 256) {
        int c = lh[i];
        lbase[i] = c ? atomicAdd(&gcursor[i], c) : 0;
    }
    __syncthreads();
#pragma unroll
    for (int k = 0; k < 4; ++k) {
        int e = e0 + k * 256 + t, src, dst;
        load_edge(er, L, e, src, dst);
        int pos = atomicAdd(&lbase[dst], 1);
        unsigned ps = ((unsigned)e << 9) | (unsigned)src;
        if (packed) {
            const float2* s = reinterpret_cast<const float2*>(ea + (size_t)e * 6);
            const float2 a0 = s[0], a1 = s[1], a2 = s[2];
            float4* d = reinterpret_cast<float4*>(eas + (size_t)pos * 8);
            d[0] = make_float4(a0.x, a0.y, a1.x, a1.y);
            d[1] = make_float4(a2.x, a2.y, __uint_as_float(ps), 0.f);
        } else {
            perm[pos] = ps;
        }
    }
}

// ---------------------------------------------------------------------------
// Edge pass: ONE WAVE PER 64-EDGE CHUNK of a dst's sorted edge list; LANE OWNS
// AN EDGE (edge-parallel — rounds 3-11 serialized one uniform edge per block
// iteration, which is why L1 cost == L2 cost). Weights stream on the scalar
// path (wave-uniform (i,o) -> one s_load_dwordx8), amortized over 64 parallel
// edges. h gathered from GLOBAL (each lane's row stays hot in L1; no LDS, no
// barriers). Chunk ends: butterfly reduce + lane-0 no-return atomics into ssum.
template <int CIN, int COUT, int HS, bool PACKED>
__global__ __launch_bounds__(256) void edge_kernel(
    const float* __restrict__ eas, const float* __restrict__ ea,
    const unsigned* __restrict__ perm, const int* __restrict__ start,
    const int* __restrict__ chstart, const int* __restrict__ chtotal,
    const int* __restrict__ map, const float* __restrict__ lwT,
    const float* __restrict__ hin, float* __restrict__ ssum)
{
    const int wid = threadIdx.x >> 6, lane = threadIdx.x & 63;
    const int chunk = blockIdx.x * 4 + wid;
    if (chunk >= chtotal[0]) return;
    const int dst = map[chunk];
    const int lc = chunk - chstart[dst];
    const int e0 = start[dst] + lc * 64;
    const int e1 = min(e0 + 64, start[dst + 1]);
    const int idx = e0 + lane;
    const bool val = (idx < e1);
    const int eidx = val ? idx : e0;

    float a0, a1, a2, a3, a4, a5;
    int src;
    if constexpr (PACKED) {
        const float4* __restrict__ b = reinterpret_cast<const float4*>(eas) + 2 * (size_t)eidx;
        const float4 r0 = b[0], r1 = b[1];
        a0 = r0.x; a1 = r0.y; a2 = r0.z; a3 = r0.w; a4 = r1.x; a5 = r1.y;
        src = (int)(__float_as_uint(r1.z) & 511u);
    } else {
        unsigned ps = perm[eidx];
        const float* __restrict__ ap = ea + (size_t)(ps >> 9) * 6;
        a0 = ap[0]; a1 = ap[1]; a2 = ap[2]; a3 = ap[3]; a4 = ap[4]; a5 = ap[5];
        src = (int)(ps & 511u);
    }

    float acc[COUT];
#pragma unroll
    for (int o = 0; o < COUT; ++o) acc[o] = 0.f;

    if constexpr (CIN == 1) {
        const float hsv = val ? hin[src] : 0.f;
#pragma unroll
        for (int o = 0; o < COUT; ++o) {
            const float* __restrict__ w8 = lwT + o * 8;   // wave-uniform -> s_load
            float tt = w8[0];
            tt = fmaf(a0, w8[1], tt); tt = fmaf(a1, w8[2], tt);
            tt = fmaf(a2, w8[3], tt); tt = fmaf(a3, w8[4], tt);
            tt = fmaf(a4, w8[5], tt); tt = fmaf(a5, w8[6], tt);
            acc[o] = fmaf(hsv, fmaxf(tt, 0.f), acc[o]);
        }
    } else {
        const float2* __restrict__ hrow = reinterpret_cast<const float2*>(hin + (size_t)src * HS);
        for (int i2 = 0; i2 < CIN / 2; ++i2) {
            float2 hv = hrow[i2];
            if (!val) { hv.x = 0.f; hv.y = 0.f; }
            const float* __restrict__ w0 = lwT + (size_t)(2 * i2) * COUT * 8;
#pragma unroll
            for (int o = 0; o < COUT; ++o) {
                const float* __restrict__ w8 = w0 + o * 8;
                float tt = w8[0];
                tt = fmaf(a0, w8[1], tt); tt = fmaf(a1, w8[2], tt);
                tt = fmaf(a2, w8[3], tt); tt = fmaf(a3, w8[4], tt);
                tt = fmaf(a4, w8[5], tt); tt = fmaf(a5, w8[6], tt);
                acc[o] = fmaf(hv.x, fmaxf(tt, 0.f), acc[o]);
            }
            const float* __restrict__ w1 = w0 + COUT * 8;
#pragma unroll
            for (int o = 0; o < COUT; ++o) {
                const float* __restrict__ w8 = w1 + o * 8;
                float tt = w8[0];
                tt = fmaf(a0, w8[1], tt); tt = fmaf(a1, w8[2], tt);
                tt = fmaf(a2, w8[3], tt); tt = fmaf(a3, w8[4], tt);
                tt = fmaf(a4, w8[5], tt); tt = fmaf(a5, w8[6], tt);
                acc[o] = fmaf(hv.y, fmaxf(tt, 0.f), acc[o]);
            }
        }
    }

    // 64-lane butterfly per o, then lane 0 fires no-return atomics
#pragma unroll
    for (int o = 0; o < COUT; ++o) {
        float v = acc[o];
#pragma unroll
        for (int d = 32; d > 0; d >>= 1) v += __shfl_xor(v, d);
        acc[o] = v;
    }
    if (lane == 0) {
        float* __restrict__ sd = ssum + (size_t)dst * COUT;
#pragma unroll
        for (int o = 0; o < COUT; ++o) atomicAdd(&sd[o], acc[o]);
    }
}

// node: mean + root term + bias + relu; strided (padded) h storage
template <int CIN, int COUT, int HSIN, int HSOUT>
__global__ __launch_bounds__(256) void node_kernel(
    const float* __restrict__ hin, const float* __restrict__ ssum,
    const int* __restrict__ start, const float* __restrict__ root,
    const float* __restrict__ bias, float* __restrict__ hout)
{
    int t = blockIdx.x * 256 + threadIdx.x;
    if (t >= NROIS * COUT) return;
    int i = t / COUT, o = t - i * COUT;
    int cnt = start[i + 1] - start[i];
    float aggr = ssum[(size_t)i * COUT + o] / fmaxf((float)cnt, 1.f);
    float r = bias[o];
#pragma unroll 4
    for (int k = 0; k < CIN; ++k)
        r = fmaf(hin[(size_t)i * HSIN + k], root[k * COUT + o], r);
    hout[(size_t)i * HSOUT + o] = fmaxf(aggr + r, 0.f);
}

// cbt[i,j] = sum_k |h[i,k]-h[j,k]|, h: [512,5] staged in LDS, block per row i
__global__ __launch_bounds__(256) void cbt_kernel(const float* __restrict__ h,
                                                  float* __restrict__ out)
{
    __shared__ float sh[NROIS * 5];
    for (int t = threadIdx.x; t < NROIS * 5; t += 256) sh[t] = h[t];
    __syncthreads();
    const int i = blockIdx.x;
    float hi[5];
#pragma unroll
    for (int k = 0; k < 5; ++k) hi[k] = sh[i * 5 + k];
    for (int j = threadIdx.x; j < NROIS; j += 256) {
        float s = 0.f;
#pragma unroll
        for (int k = 0; k < 5; ++k) s += fabsf(hi[k] - sh[j * 5 + k]);
        out[i * NROIS + j] = s;
    }
}

// ---------------------------------------------------------------------------
template <bool PACKED>
static void run_layers(const float* x, const float* ea, const unsigned* perm,
                       const int* start, const int* chstart, const int* chtotal,
                       const int* map,
                       const float* lwT1, const float* root1, const float* b1,
                       const float* lwT2, const float* root2, const float* b2,
                       const float* lwT3, const float* root3, const float* b3,
                       const float* eas, float* s1, float* s2, float* s3,
                       float* h1, float* h2, float* h3, hipStream_t stream)
{
    const int EB = NCHMAX / 4;   // 1152 blocks x 4 waves
    // layer 1: cin=1, cout=36
    edge_kernel<1, 36, 1, PACKED><<<EB, 256, 0, stream>>>(
        eas, ea, perm, start, chstart, chtotal, map, lwT1, x, s1);
    node_kernel<1, 36, 1, 40><<<(NROIS * 36 + 255) / 256, 256, 0, stream>>>(
        x, s1, start, root1, b1, h1);
    // layer 2: cin=36, cout=24 (h1 rows padded to 40)
    edge_kernel<36, 24, 40, PACKED><<<EB, 256, 0, stream>>>(
        eas, ea, perm, start, chstart, chtotal, map, lwT2, h1, s2);
    node_kernel<36, 24, 40, 28><<<(NROIS * 24 + 255) / 256, 256, 0, stream>>>(
        h1, s2, start, root2, b2, h2);
    // layer 3: cin=24, cout=5 (h2 rows padded to 28)
    edge_kernel<24, 5, 28, PACKED><<<EB, 256, 0, stream>>>(
        eas, ea, perm, start, chstart, chtotal, map, lwT3, h2, s3);
    node_kernel<24, 5, 28, 5><<<(NROIS * 5 + 255) / 256, 256, 0, stream>>>(
        h2, s3, start, root3, b3, h3);
}

extern "C" void kernel_launch(void* const* d_in, const int* in_sizes, int n_in,
                              void* d_out, int out_size, void* d_ws, size_t ws_size,
                              hipStream_t stream)
{
    const float*    x     = (const float*)d_in[0];
    const float*    ea    = (const float*)d_in[1];
    const unsigned* er    = (const unsigned*)d_in[2];
    const float*    lw1   = (const float*)d_in[3];
    const float*    lb1   = (const float*)d_in[4];
    const float*    root1 = (const float*)d_in[5];
    const float*    b1    = (const float*)d_in[6];
    const float*    lw2   = (const float*)d_in[7];
    const float*    lb2   = (const float*)d_in[8];
    const float*    root2 = (const float*)d_in[9];
    const float*    b2    = (const float*)d_in[10];
    const float*    lw3   = (const float*)d_in[11];
    const float*    lb3   = (const float*)d_in[12];
    const float*    root3 = (const float*)d_in[13];
    const float*    b3    = (const float*)d_in[14];

    const size_t easN  = (size_t)NEDGES * 8;     // floats
    // floats: lwT(8160) + h1(20480) + h2(14336) + h3(2560) + ssum(33280)
    // ints:   start(513) + cursor(512) + chstart(513) + chtotal(1) + map(4608) + perm(E)
    const size_t restN = 8160 + 20480 + 14336 + 2560 + 33280
                       + 513 + 512 + 513 + 1 + NCHMAX + NEDGES;
    const size_t needPacked = (easN + restN) * 4;
    const int packed = (ws_size >= needPacked) ? 1 : 0;

    float* ws   = (float*)d_ws;
    float* eas  = ws;                                   // 8 MB (packed only)
    float* rest = packed ? (ws + easN) : ws;
    float* lwT1 = rest;                  // 288
    float* lwT2 = lwT1 + 288;            // 6912
    float* lwT3 = lwT2 + 6912;           // 960
    float* h1   = lwT3 + 960;            // 512*40
    float* h2   = h1 + NROIS * 40;       // 512*28
    float* h3   = h2 + NROIS * 28;       // 512*5
    float* s1   = h3 + NROIS * 5;        // 512*36
    float* s2   = s1 + NROIS * 36;       // 512*24
    float* s3   = s2 + NROIS * 24;       // 512*5
    int* gpart  = (int*)s1;              // 64*512 ints alias (pre-zero phase only)
    int* start  = (int*)(s3 + NROIS * 5);
    int* cursor = start + NROIS + 1;     // 512
    int* chstart = cursor + NROIS;       // 513
    int* chtotal = chstart + NROIS + 1;  // 1
    int* map     = chtotal + 1;          // 4608
    unsigned* perm = (unsigned*)(map + NCHMAX);         // 262144

    // --- prep + counting sort by dst + wave-chunk map + packed edge rows ---
    prep_kernel<<<1, 256, 0, stream>>>(lw1, lb1, lw2, lb2, lw3, lb3,
                                       lwT1, lwT2, lwT3);
    hist_kernel<<<NEDGES / 4096, 256, 0, stream>>>(er, gpart);
    scan_kernel<<<1, 512, 0, stream>>>(gpart, start, cursor, chstart, chtotal, map);
    scatter_kernel<<<NEDGES / 1024, 256, 0, stream>>>(er, ea, cursor, perm, eas, packed);
    zero_kernel<<<(NROIS * 65 + 255) / 256, 256, 0, stream>>>(s1, NROIS * 65);

    if (packed)
        run_layers<true>(x, ea, perm, start, chstart, chtotal, map,
                         lwT1, root1, b1, lwT2, root2, b2, lwT3, root3, b3,
                         eas, s1, s2, s3, h1, h2, h3, stream);
    else
        run_layers<false>(x, ea, perm, start, chstart, chtotal, map,
                          lwT1, root1, b1, lwT2, root2, b2, lwT3, root3, b3,
                          eas, s1, s2, s3, h1, h2, h3, stream);

    // --- pairwise L1 distance tail ---
    cbt_kernel<<<NROIS, 256, 0, stream>>>(h3, (float*)d_out);
}